// Round 1
// baseline (8299.773 us; speedup 1.0000x reference)
//
#include <hip/hip_runtime.h>
#include <hip/hip_cooperative_groups.h>
#include <math.h>

namespace cg = cooperative_groups;

#define BS 64
#define N 1024
#define BPB 8                           // blocks per batch
#define ROWS_PER_BLOCK (N / BPB)        // 128
#define THREADS 256
#define WAVES (THREADS / 64)            // 4
#define ROWS_PER_WAVE (ROWS_PER_BLOCK / WAVES)  // 32
#define KSTRIDE 64                      // per-batch scalar-history stride (>= maxiter+1)

// ws layout (floats):
//   rz  [BS][KSTRIDE]
//   pAp [BS][KSTRIDE]
//   rn2 [BS][KSTRIDE]
//   r   [BS][N]
//   z   [BS][N]
//   p0  [BS][N]
//   p1  [BS][N]
//   d   [BS][N]   (diagonal of M_inv)

__device__ inline float wave_reduce(float v) {
#pragma unroll
    for (int off = 32; off > 0; off >>= 1) v += __shfl_xor(v, off, 64);
    return v;
}

__device__ inline float row_dot(const float4* __restrict__ arow,
                                const float4* __restrict__ pl4, int lane) {
    // Issue all 4 global float4 loads up front for ILP / outstanding loads.
    float4 va0 = arow[lane];
    float4 va1 = arow[lane + 64];
    float4 va2 = arow[lane + 128];
    float4 va3 = arow[lane + 192];
    float4 vp0 = pl4[lane];
    float4 vp1 = pl4[lane + 64];
    float4 vp2 = pl4[lane + 128];
    float4 vp3 = pl4[lane + 192];
    float a0 = va0.x * vp0.x + va0.y * vp0.y + va0.z * vp0.z + va0.w * vp0.w;
    float a1 = va1.x * vp1.x + va1.y * vp1.y + va1.z * vp1.z + va1.w * vp1.w;
    float a2 = va2.x * vp2.x + va2.y * vp2.y + va2.z * vp2.z + va2.w * vp2.w;
    float a3 = va3.x * vp3.x + va3.y * vp3.y + va3.z * vp3.z + va3.w * vp3.w;
    return (a0 + a1) + (a2 + a3);
}

// Matvec over this block's row chunk using p in LDS. Writes row sums to ap_lds.
// Returns this wave's partial p.Ap (identical across lanes of the wave).
template <bool ACC_PAP>
__device__ inline float matvec_chunk(const float* __restrict__ Ab,
                                     const float* __restrict__ p_lds,
                                     float* __restrict__ ap_lds,
                                     int row0, int wave, int lane) {
    const float4* pl4 = (const float4*)p_lds;
    float pap = 0.f;
#pragma unroll 1
    for (int rr = 0; rr < ROWS_PER_WAVE; ++rr) {
        int rowl = wave * ROWS_PER_WAVE + rr;
        int row = row0 + rowl;
        const float4* arow = (const float4*)(Ab + (size_t)row * N);
        float s = row_dot(arow, pl4, lane);
        s = wave_reduce(s);
        if (lane == 0) ap_lds[rowl] = s;
        if (ACC_PAP) pap += s * p_lds[row];  // LDS broadcast, uniform across lanes
    }
    return pap;
}

__global__ __launch_bounds__(THREADS, 2) void pcg_kernel(
    const float* __restrict__ A, const float* __restrict__ b,
    const float* __restrict__ x0, const float* __restrict__ Minv,
    const int* __restrict__ maxiter_p, float* __restrict__ out,
    float* __restrict__ ws) {
    cg::grid_group grid = cg::this_grid();

    const int blk = blockIdx.x;
    const int batch = blk / BPB;
    const int chunk = blk % BPB;
    const int row0 = chunk * ROWS_PER_BLOCK;
    const int tid = threadIdx.x;
    const int lane = tid & 63;
    const int wave = tid >> 6;

    float* rz = ws;                       // [BS][KSTRIDE]
    float* pAp = ws + BS * KSTRIDE;       // [BS][KSTRIDE]
    float* rn2 = ws + 2 * BS * KSTRIDE;   // [BS][KSTRIDE]
    float* rv = ws + 3 * BS * KSTRIDE;
    float* zv = rv + (size_t)BS * N;
    float* pv0 = zv + (size_t)BS * N;
    float* pv1 = pv0 + (size_t)BS * N;
    float* dv = pv1 + (size_t)BS * N;

    const float* Ab = A + (size_t)batch * N * N;
    const float* bb = b + (size_t)batch * N;
    const float* x0b = x0 + (size_t)batch * N;
    float* rb = rv + (size_t)batch * N;
    float* zb = zv + (size_t)batch * N;
    float* db = dv + (size_t)batch * N;

    const int maxiter = maxiter_p[0];  // 50
    const int outw = maxiter + 1;

    __shared__ float p_lds[N];
    __shared__ float ap_lds[ROWS_PER_BLOCK];

    // ---------- init: r0 = b - A x0, z0 = d .* r0, p0 = z0 ----------
    for (int i = tid; i < N; i += THREADS) p_lds[i] = x0b[i];
    __syncthreads();
    matvec_chunk<false>(Ab, p_lds, ap_lds, row0, wave, lane);
    __syncthreads();
    if (tid < ROWS_PER_BLOCK) {
        int row = row0 + tid;
        float r0 = bb[row] - ap_lds[tid];
        float d = Minv[((size_t)batch * N + row) * N + row];  // diagonal extract
        float z0 = d * r0;
        rb[row] = r0;
        zb[row] = z0;
        db[row] = d;
        pv0[(size_t)batch * N + row] = z0;
        float wrz = wave_reduce(r0 * z0);
        float wrn = wave_reduce(r0 * r0);
        if (lane == 0) {
            atomicAdd(&rz[batch * KSTRIDE + 0], wrz);
            atomicAdd(&rn2[batch * KSTRIDE + 0], wrn);
        }
    }
    grid.sync();

    // ---------- main loop ----------
    for (int k = 1; k <= maxiter; ++k) {
        const float* pprevb =
            ((k & 1) ? pv0 : pv1) + (size_t)batch * N;  // buffer (k-1)&1
        float* pcurb = ((k & 1) ? pv1 : pv0) + (size_t)batch * N;

        // out[b][k-1] (rn2[k-1] finalized before last grid sync)
        if (chunk == 0 && tid == 0)
            out[batch * outw + (k - 1)] = sqrtf(rn2[batch * KSTRIDE + (k - 1)]);

        float beta = 0.f;
        if (k >= 2)
            beta = rz[batch * KSTRIDE + (k - 1)] / rz[batch * KSTRIDE + (k - 2)];

        // Phase A: rebuild p_cur = z + beta * p_prev redundantly, publish chunk,
        // matvec + partial p.Ap
        for (int i = tid; i < N; i += THREADS)
            p_lds[i] = zb[i] + beta * pprevb[i];
        __syncthreads();
        if (tid < ROWS_PER_BLOCK)
            pcurb[row0 + tid] = p_lds[row0 + tid];
        float pap = matvec_chunk<true>(Ab, p_lds, ap_lds, row0, wave, lane);
        if (lane == 0) atomicAdd(&pAp[batch * KSTRIDE + k], pap);
        grid.sync();

        // Phase B: alpha, update r/z, accumulate rz_new and ||r||^2
        float alpha =
            rz[batch * KSTRIDE + (k - 1)] / pAp[batch * KSTRIDE + k];
        if (tid < ROWS_PER_BLOCK) {
            int row = row0 + tid;
            float rnew = rb[row] - alpha * ap_lds[tid];
            float znew = db[row] * rnew;
            rb[row] = rnew;
            zb[row] = znew;
            float wrz = wave_reduce(rnew * znew);
            float wrn = wave_reduce(rnew * rnew);
            if (lane == 0) {
                atomicAdd(&rz[batch * KSTRIDE + k], wrz);
                atomicAdd(&rn2[batch * KSTRIDE + k], wrn);
            }
        }
        grid.sync();
    }

    // final history entry
    if (chunk == 0 && tid == 0)
        out[batch * outw + maxiter] = sqrtf(rn2[batch * KSTRIDE + maxiter]);
}

extern "C" void kernel_launch(void* const* d_in, const int* in_sizes, int n_in,
                              void* d_out, int out_size, void* d_ws,
                              size_t ws_size, hipStream_t stream) {
    const float* A = (const float*)d_in[0];
    const float* b = (const float*)d_in[1];
    const float* x0 = (const float*)d_in[2];
    const float* Minv = (const float*)d_in[3];
    // d_in[4] = rtol (unused by the reference recurrence)
    const int* maxiter = (const int*)d_in[5];
    float* out = (float*)d_out;
    float* ws = (float*)d_ws;

    // zero the scalar-accumulator region (rz, pAp, rn2)
    hipMemsetAsync(ws, 0, (size_t)3 * BS * KSTRIDE * sizeof(float), stream);

    void* args[] = {(void*)&A,       (void*)&b,   (void*)&x0, (void*)&Minv,
                    (void*)&maxiter, (void*)&out, (void*)&ws};
    dim3 grid(BS * BPB), block(THREADS);
    hipLaunchCooperativeKernel((void*)pcg_kernel, grid, block, args, 0, stream);
}